// Round 1
// baseline (1136.839 us; speedup 1.0000x reference)
//
#include <hip/hip_runtime.h>

// Problem geometry (fixed): B=4, C=512, H=64, W=64, 4C=2048
#define NB 4
#define CB 512
#define HH 64
#define WW 64
#define HW (HH*WW)      // 4096
#define C4 (4*CB)       // 2048

__device__ __forceinline__ float relu_f(float v){ return v > 0.f ? v : 0.f; }

// ---------------------------------------------------------------------------
// conv1x1 as GEMM: Y[b][o][p] = sum_i Wm[o*IC+i] * X[b*IC*P + i*P + p]
// Tile 128x128, K-step 8, 256 threads, 8x8 per thread, fp32 vector FMA.
// grid = (P/128, OC/128, B)
// ---------------------------------------------------------------------------
template<int RELU>
__global__ __launch_bounds__(256) void conv1x1_kernel(
    const float* __restrict__ X, const float* __restrict__ Wm,
    float* __restrict__ Y, int OC, int IC, int P)
{
    __shared__ float As[8][128];   // As[k][m] = Wm[m0+m][k0+k]
    __shared__ float Bs[8][128];   // Bs[k][n] = X[k0+k][n0+n]

    const float* Xb = X + (size_t)blockIdx.z * IC * P;
    float*       Yb = Y + (size_t)blockIdx.z * OC * P;
    const int m0 = blockIdx.y * 128;
    const int n0 = blockIdx.x * 128;
    const int t  = threadIdx.x;
    const int tx = t & 15;        // 0..15 -> n sub-tile
    const int ty = t >> 4;        // 0..15 -> m sub-tile

    float acc[8][8];
    #pragma unroll
    for (int i = 0; i < 8; i++)
        #pragma unroll
        for (int j = 0; j < 8; j++) acc[i][j] = 0.f;

    for (int k0 = 0; k0 < IC; k0 += 8) {
        // load W tile: 128 m x 8 k (1024 elems, 4/thread)
        #pragma unroll
        for (int i = 0; i < 4; i++) {
            int idx = t + i*256;
            int m = idx >> 3, k = idx & 7;
            As[k][m] = Wm[(size_t)(m0+m)*IC + (k0+k)];
        }
        // load X tile: 8 k x 128 n (coalesced 512B rows)
        #pragma unroll
        for (int i = 0; i < 4; i++) {
            int idx = t + i*256;
            int k = idx >> 7, n = idx & 127;
            Bs[k][n] = Xb[(size_t)(k0+k)*P + (n0+n)];
        }
        __syncthreads();
        #pragma unroll
        for (int k = 0; k < 8; k++) {
            float4 a0 = *(const float4*)&As[k][ty*8];
            float4 a1 = *(const float4*)&As[k][ty*8+4];
            float4 b0 = *(const float4*)&Bs[k][tx*8];
            float4 b1 = *(const float4*)&Bs[k][tx*8+4];
            float a[8] = {a0.x,a0.y,a0.z,a0.w,a1.x,a1.y,a1.z,a1.w};
            float b[8] = {b0.x,b0.y,b0.z,b0.w,b1.x,b1.y,b1.z,b1.w};
            #pragma unroll
            for (int i = 0; i < 8; i++)
                #pragma unroll
                for (int j = 0; j < 8; j++)
                    acc[i][j] = fmaf(a[i], b[j], acc[i][j]);
        }
        __syncthreads();
    }

    #pragma unroll
    for (int i = 0; i < 8; i++) {
        float* yr = Yb + (size_t)(m0 + ty*8 + i)*P + n0 + tx*8;
        float4 v0 = make_float4(acc[i][0],acc[i][1],acc[i][2],acc[i][3]);
        float4 v1 = make_float4(acc[i][4],acc[i][5],acc[i][6],acc[i][7]);
        if (RELU) {
            v0.x=relu_f(v0.x); v0.y=relu_f(v0.y); v0.z=relu_f(v0.z); v0.w=relu_f(v0.w);
            v1.x=relu_f(v1.x); v1.y=relu_f(v1.y); v1.z=relu_f(v1.z); v1.w=relu_f(v1.w);
        }
        *(float4*)yr     = v0;
        *(float4*)(yr+4) = v1;
    }
}

// ---------------------------------------------------------------------------
// Vertical IRNN scan (axis=H). One thread per (b,c,w) sequence; lanes span w
// -> every step is a fully coalesced 256B access per wave.
// Semantics (jax.lax.scan in reference):
//   scan-order pos 0 output = 0 ; h0 = relu(x0) ; h_t = relu(h_{t-1}*w+b+x_t)
// dst is the concat buffer (B, 2048, H, W); dirOff = channel offset.
// ---------------------------------------------------------------------------
__global__ __launch_bounds__(256) void scan_vert_kernel(
    const float* __restrict__ src, float* __restrict__ dst,
    const float* __restrict__ wv, const float* __restrict__ bv,
    int reverse, int dirOff)
{
    int idx = blockIdx.x * blockDim.x + threadIdx.x;   // B*C*W = 131072
    int w  = idx & (WW-1);
    int bc = idx >> 6;            // b*C + c
    int c  = bc & (CB-1);
    int b  = bc >> 9;
    const float* in  = src + (size_t)bc * HW + w;
    float*       out = dst + ((size_t)(b*C4 + dirOff + c)) * HW + w;
    float wc = wv[c], bb = bv[c];

    if (!reverse) {   // down: scan h = 0 .. 63
        float s = relu_f(in[0]);
        out[0] = 0.f;
        #pragma unroll 4
        for (int h = 1; h < HH; h++) {
            s = relu_f(fmaf(s, wc, bb + in[h*WW]));
            out[h*WW] = s;
        }
    } else {          // up: scan h = 63 .. 0
        float s = relu_f(in[(HH-1)*WW]);
        out[(HH-1)*WW] = 0.f;
        #pragma unroll 4
        for (int h = HH-2; h >= 0; h--) {
            s = relu_f(fmaf(s, wc, bb + in[h*WW]));
            out[h*WW] = s;
        }
    }
}

// ---------------------------------------------------------------------------
// Horizontal IRNN scan (axis=W). One thread per (b,c,h) row (contiguous),
// float4-chunked loads/stores (rows are 16B-aligned: offsets are x64 floats).
// ---------------------------------------------------------------------------
__global__ __launch_bounds__(256) void scan_horiz_kernel(
    const float* __restrict__ src, float* __restrict__ dst,
    const float* __restrict__ wv, const float* __restrict__ bv,
    int reverse, int dirOff)
{
    int idx = blockIdx.x * blockDim.x + threadIdx.x;   // B*C*H = 131072
    int h  = idx & (HH-1);
    int bc = idx >> 6;
    int c  = bc & (CB-1);
    int b  = bc >> 9;
    const float* in  = src + ((size_t)bc * HH + h) * WW;
    float*       out = dst + ((size_t)(b*C4 + dirOff + c) * HH + h) * WW;
    float wc = wv[c], bb = bv[c];

    if (!reverse) {   // right: w = 0 .. 63
        float s;
        {
            float4 x4 = *(const float4*)(in);
            float4 y4;
            s = relu_f(x4.x);                    y4.x = 0.f;
            s = relu_f(fmaf(s, wc, bb + x4.y));  y4.y = s;
            s = relu_f(fmaf(s, wc, bb + x4.z));  y4.z = s;
            s = relu_f(fmaf(s, wc, bb + x4.w));  y4.w = s;
            *(float4*)(out) = y4;
        }
        for (int q = 1; q < WW/4; q++) {
            float4 x4 = *(const float4*)(in + q*4);
            float4 y4;
            s = relu_f(fmaf(s, wc, bb + x4.x));  y4.x = s;
            s = relu_f(fmaf(s, wc, bb + x4.y));  y4.y = s;
            s = relu_f(fmaf(s, wc, bb + x4.z));  y4.z = s;
            s = relu_f(fmaf(s, wc, bb + x4.w));  y4.w = s;
            *(float4*)(out + q*4) = y4;
        }
    } else {          // left: w = 63 .. 0
        float s;
        {
            float4 x4 = *(const float4*)(in + WW - 4);
            float4 y4;
            s = relu_f(x4.w);                    y4.w = 0.f;
            s = relu_f(fmaf(s, wc, bb + x4.z));  y4.z = s;
            s = relu_f(fmaf(s, wc, bb + x4.y));  y4.y = s;
            s = relu_f(fmaf(s, wc, bb + x4.x));  y4.x = s;
            *(float4*)(out + WW - 4) = y4;
        }
        for (int q = WW/4 - 2; q >= 0; q--) {
            float4 x4 = *(const float4*)(in + q*4);
            float4 y4;
            s = relu_f(fmaf(s, wc, bb + x4.w));  y4.w = s;
            s = relu_f(fmaf(s, wc, bb + x4.z));  y4.z = s;
            s = relu_f(fmaf(s, wc, bb + x4.y));  y4.y = s;
            s = relu_f(fmaf(s, wc, bb + x4.x));  y4.x = s;
            *(float4*)(out + q*4) = y4;
        }
    }
}

// ---------------------------------------------------------------------------
// Launch. Note: the reference's conv3x3/sigmoid "attention" branch computes
// `_weight`, which is never used in the returned output -> skipped entirely.
// Buffers: d_out doubles as out0/mid scratch (fully rewritten at the end);
// d_ws[0 .. 128MB) holds the (B, 2048, H, W) concat buffer.
// ---------------------------------------------------------------------------
extern "C" void kernel_launch(void* const* d_in, const int* in_sizes, int n_in,
                              void* d_out, int out_size, void* d_ws, size_t ws_size,
                              hipStream_t stream) {
    const float* x     = (const float*)d_in[0];
    const float* cin_w = (const float*)d_in[7];
    const float* c2_w  = (const float*)d_in[8];
    const float* c3_w  = (const float*)d_in[9];
    // i1: wu,bu, wr,br, wd,bd, wl,bl at indices 10..17 ; i2 at 18..25
    const float* i1_wu = (const float*)d_in[10];
    const float* i1_bu = (const float*)d_in[11];
    const float* i1_wr = (const float*)d_in[12];
    const float* i1_br = (const float*)d_in[13];
    const float* i1_wd = (const float*)d_in[14];
    const float* i1_bd = (const float*)d_in[15];
    const float* i1_wl = (const float*)d_in[16];
    const float* i1_bl = (const float*)d_in[17];
    const float* i2_wu = (const float*)d_in[18];
    const float* i2_bu = (const float*)d_in[19];
    const float* i2_wr = (const float*)d_in[20];
    const float* i2_br = (const float*)d_in[21];
    const float* i2_wd = (const float*)d_in[22];
    const float* i2_bd = (const float*)d_in[23];
    const float* i2_wl = (const float*)d_in[24];
    const float* i2_bl = (const float*)d_in[25];

    float* out    = (float*)d_out;            // (B,512,H,W) = 32 MB, reused as out0/mid
    float* concat = (float*)d_ws;             // (B,2048,H,W) = 128 MB

    dim3 gemm_grid(HW/128, CB/128, NB);       // 32 x 4 x 4 = 512 blocks
    const int scan_blocks = (NB*CB*WW) / 256; // 512

    // 1) out0 = cin_w @ x
    conv1x1_kernel<0><<<gemm_grid, 256, 0, stream>>>(x, cin_w, out, CB, CB, HW);

    // 2) IRNN #1: out0 -> concat [u | r | d | l]
    scan_vert_kernel <<<scan_blocks, 256, 0, stream>>>(out, concat, i1_wu, i1_bu, 1, 0);
    scan_horiz_kernel<<<scan_blocks, 256, 0, stream>>>(out, concat, i1_wr, i1_br, 0, CB);
    scan_vert_kernel <<<scan_blocks, 256, 0, stream>>>(out, concat, i1_wd, i1_bd, 0, 2*CB);
    scan_horiz_kernel<<<scan_blocks, 256, 0, stream>>>(out, concat, i1_wl, i1_bl, 1, 3*CB);

    // 3) mid = c2_w @ concat
    conv1x1_kernel<0><<<gemm_grid, 256, 0, stream>>>(concat, c2_w, out, CB, C4, HW);

    // 4) IRNN #2: mid -> concat
    scan_vert_kernel <<<scan_blocks, 256, 0, stream>>>(out, concat, i2_wu, i2_bu, 1, 0);
    scan_horiz_kernel<<<scan_blocks, 256, 0, stream>>>(out, concat, i2_wr, i2_br, 0, CB);
    scan_vert_kernel <<<scan_blocks, 256, 0, stream>>>(out, concat, i2_wd, i2_bd, 0, 2*CB);
    scan_horiz_kernel<<<scan_blocks, 256, 0, stream>>>(out, concat, i2_wl, i2_bl, 1, 3*CB);

    // 5) out = relu(c3_w @ concat)
    conv1x1_kernel<1><<<gemm_grid, 256, 0, stream>>>(concat, c3_w, out, CB, C4, HW);
}

// Round 2
// 218.738 us; speedup vs baseline: 5.1973x; 5.1973x over previous
//
#include <hip/hip_runtime.h>
#include <stdint.h>

// Geometry (fixed): B=4, C=512, H=W=64
#define NB 4
#define CB 512
#define HH 64
#define WW 64
#define HW 4096
#define C4 2048
#define PTOT (NB*HW)   // 16384 "pixels" across batch (batch-major, contiguous)

typedef float  f32x4  __attribute__((ext_vector_type(4)));
typedef short  bf16x8 __attribute__((ext_vector_type(8)));

__device__ __forceinline__ float relu_f(float v){ return v > 0.f ? v : 0.f; }

__device__ __forceinline__ float bf2f(unsigned short u){
    union { uint32_t i; float f; } v; v.i = ((uint32_t)u) << 16; return v.f;
}
__device__ __forceinline__ unsigned short f2bf(float f){
    union { float f; uint32_t i; } v; v.f = f;
    uint32_t r = v.i + 0x7FFFu + ((v.i >> 16) & 1u);   // RNE
    return (unsigned short)(r >> 16);
}

// async global->LDS, 16B per lane; lds ptr must be wave-uniform base (+lane*16 implicit)
__device__ __forceinline__ void gload16(const void* g, void* l){
    __builtin_amdgcn_global_load_lds(
        (const __attribute__((address_space(1))) uint32_t*)g,
        (__attribute__((address_space(3))) uint32_t*)l, 16, 0, 0);
}

// ---------------------------------------------------------------------------
// fp32 -> bf16 elementwise cast (n divisible by 1024)
// ---------------------------------------------------------------------------
__global__ __launch_bounds__(256) void cast_f32_bf16(
    const float* __restrict__ in, unsigned short* __restrict__ out)
{
    int i = blockIdx.x * 256 + threadIdx.x;
    float4 v = ((const float4*)in)[i];
    ushort4 o;
    o.x = f2bf(v.x); o.y = f2bf(v.y); o.z = f2bf(v.z); o.w = f2bf(v.w);
    ((ushort4*)out)[i] = o;
}

// ---------------------------------------------------------------------------
// x [b][c][p] fp32  ->  xT [b*HW + p][c] bf16   (64x64 LDS tile transpose)
// grid: (HW/64, CB/64, NB), 256 threads
// ---------------------------------------------------------------------------
__global__ __launch_bounds__(256) void transpose_cast_x(
    const float* __restrict__ x, unsigned short* __restrict__ xT)
{
    __shared__ unsigned short tile[64][72];   // pad: row stride 144B (8B-aligned)
    const int b  = blockIdx.z;
    const int p0 = blockIdx.x * 64;
    const int c0 = blockIdx.y * 64;
    const int t  = threadIdx.x;

    const int pl = (t & 15) * 4;  // 0..60
    const int cl = t >> 4;        // 0..15
    const float* src = x + ((size_t)b * CB + c0) * HW + p0;
    #pragma unroll
    for (int r = 0; r < 4; r++) {
        int c = cl + r * 16;
        float4 v = *(const float4*)(src + (size_t)c * HW + pl);
        tile[pl + 0][c] = f2bf(v.x);
        tile[pl + 1][c] = f2bf(v.y);
        tile[pl + 2][c] = f2bf(v.z);
        tile[pl + 3][c] = f2bf(v.w);
    }
    __syncthreads();
    unsigned short* dst = xT + ((size_t)b * HW + p0) * CB + c0;
    const int cl2 = (t & 15) * 4;
    const int pl2 = t >> 4;
    #pragma unroll
    for (int r = 0; r < 4; r++) {
        int p = pl2 + r * 16;
        ushort4 o = *(ushort4*)&tile[p][cl2];
        *(ushort4*)(dst + (size_t)p * CB + cl2) = o;
    }
}

// ---------------------------------------------------------------------------
// Channel-last MFMA GEMM: D[p][o] = sum_k A[p][k] * Bw[o][k]   (bf16 in, f32 acc)
//   A  : [PTOT][K] bf16 (k-major)   Bw : [512][K] bf16 (k-major)
// Tile 128p x 128o, BK=64, 4 waves (256 thr), 4x4 16x16x32 frags per wave.
// Staging: global_load_lds w=16, LDS linear, source pre-swizzled (row&7)<<4.
// OUTMODE 0: out bf16 [PTOT][512] (channel-last)
// OUTMODE 1: out fp32 [b][512][HW] (channel-first) + ReLU, LDS-transpose epilogue
// ---------------------------------------------------------------------------
template<int K, int OUTMODE>
__global__ __launch_bounds__(256) void gemm_cl(
    const unsigned short* __restrict__ A,
    const unsigned short* __restrict__ Bw,
    void* __restrict__ out)
{
    __shared__ __align__(16) char lds[34048];   // A:[0,16K) B:[16K,32K); epi f32[64][132]
    char* ldsA = lds;
    char* ldsB = lds + 16384;

    const int t    = threadIdx.x;
    const int lane = t & 63;
    const int wid  = t >> 6;
    const int p0   = blockIdx.x * 128;
    const int o0   = blockIdx.y * 128;

    const int l15 = lane & 15;
    const int l4  = lane >> 4;            // 0..3
    const int wp  = (wid & 1) * 64;       // wave p-offset
    const int wo  = (wid >> 1) * 64;      // wave o-offset
    const int rowA = wp + l15;
    const int rowB = wo + l15;
    const int swzA = (rowA & 7) << 4;
    const int swzB = (rowB & 7) << 4;

    f32x4 acc[4][4];
    #pragma unroll
    for (int m = 0; m < 4; m++)
        #pragma unroll
        for (int n = 0; n < 4; n++) acc[m][n] = (f32x4)0.f;

    // staging decode: thread t, round q: LDS byte d = q*4096 + t*16
    const int srow  = t >> 3;          // 0..31 (+q*32)
    const int scolb = (t & 7) * 16;    // byte col in 128B row

    #pragma unroll 2
    for (int k0 = 0; k0 < K; k0 += 64) {
        #pragma unroll
        for (int q = 0; q < 4; q++) {
            const int row = q * 32 + srow;
            const int kk  = k0 + ((scolb ^ ((row & 7) << 4)) >> 1);
            char* lbase = (char*)(lds) + q * 4096 + wid * 1024;          // A region
            gload16(A  + (size_t)(p0 + row) * K + kk, ldsA + q * 4096 + wid * 1024);
            gload16(Bw + (size_t)(o0 + row) * K + kk, ldsB + q * 4096 + wid * 1024);
            (void)lbase;
        }
        __syncthreads();
        #pragma unroll
        for (int kh = 0; kh < 2; kh++) {
            const int colb = kh * 64 + l4 * 16;
            bf16x8 a[4], b[4];
            #pragma unroll
            for (int m = 0; m < 4; m++)
                a[m] = *(const bf16x8*)(ldsA + (rowA + m * 16) * 128 + (colb ^ swzA));
            #pragma unroll
            for (int n = 0; n < 4; n++)
                b[n] = *(const bf16x8*)(ldsB + (rowB + n * 16) * 128 + (colb ^ swzB));
            #pragma unroll
            for (int m = 0; m < 4; m++)
                #pragma unroll
                for (int n = 0; n < 4; n++)
                    acc[m][n] = __builtin_amdgcn_mfma_f32_16x16x32_bf16(
                                    a[m], b[n], acc[m][n], 0, 0, 0);
        }
        __syncthreads();
    }

    if (OUTMODE == 0) {
        // bf16 channel-last: D[p][o], lanes 0-15 -> consecutive o (32B segments)
        unsigned short* op = (unsigned short*)out;
        #pragma unroll
        for (int m = 0; m < 4; m++)
            #pragma unroll
            for (int r = 0; r < 4; r++) {
                const int p = p0 + wp + m * 16 + l4 * 4 + r;
                #pragma unroll
                for (int n = 0; n < 4; n++) {
                    const int o = o0 + wo + n * 16 + l15;
                    op[(size_t)p * CB + o] = f2bf(acc[m][n][r]);
                }
            }
    } else {
        // fp32 channel-first + ReLU via LDS transpose (two o-halves of 64)
        float (*tl)[132] = (float(*)[132])lds;
        const int bb   = p0 >> 12;          // batch (tile lies in one batch)
        const int phw0 = p0 & (HW - 1);
        #pragma unroll
        for (int half = 0; half < 2; half++) {
            if ((wid >> 1) == half) {
                #pragma unroll
                for (int n = 0; n < 4; n++)
                    #pragma unroll
                    for (int m = 0; m < 4; m++)
                        #pragma unroll
                        for (int r = 0; r < 4; r++)
                            tl[n * 16 + l15][wp + m * 16 + l4 * 4 + r] = acc[m][n][r];
            }
            __syncthreads();
            const int orow = t >> 2;            // 0..63
            const int pseg = (t & 3) * 32;      // 0..96
            float* dst = (float*)out +
                ((size_t)(bb * CB + o0 + half * 64 + orow)) * HW + phw0 + pseg;
            #pragma unroll
            for (int j = 0; j < 8; j++) {
                float4 v = *(float4*)&tl[orow][pseg + j * 4];
                v.x = relu_f(v.x); v.y = relu_f(v.y); v.z = relu_f(v.z); v.w = relu_f(v.w);
                *(float4*)(dst + j * 4) = v;
            }
            __syncthreads();
        }
    }
}

// ---------------------------------------------------------------------------
// Channel-last IRNN scan. Thread = (b, line f, 4-channel group g).
// p(t) = f*fstep + t*pstep ; vertical: fstep=1,pstep=64 ; horizontal: fstep=64,pstep=1
// in: [PTOT][512] bf16 ; out: [PTOT][2048] bf16 at channel dirOff.
// Scan semantics: out[t0]=0; s=relu(x[t0]); s=relu(s*w+b+x[t]); out[t]=s.
// ---------------------------------------------------------------------------
__global__ __launch_bounds__(256) void scan_cl(
    const unsigned short* __restrict__ in, unsigned short* __restrict__ outc,
    const float* __restrict__ wv, const float* __restrict__ bv,
    int fstep, int pstep, int reverse, int dirOff)
{
    const int idx = blockIdx.x * 256 + threadIdx.x;   // 4*64*128 = 32768
    const int g = idx & 127;
    const int f = (idx >> 7) & 63;
    const int b = idx >> 13;
    const int c = g * 4;

    const size_t pbase = (size_t)b * HW;
    const unsigned short* ip = in   + pbase * CB + c;
    unsigned short*       op = outc + pbase * C4 + dirOff + c;

    const float4 w4 = *(const float4*)(wv + c);
    const float4 b4 = *(const float4*)(bv + c);

    const int t0 = reverse ? 63 : 0;
    const int dt = reverse ? -1 : 1;
    const int pb = f * fstep;

    ushort4 xv = *(const ushort4*)(ip + (size_t)(pb + t0 * pstep) * CB);
    float s0 = relu_f(bf2f(xv.x));
    float s1 = relu_f(bf2f(xv.y));
    float s2 = relu_f(bf2f(xv.z));
    float s3 = relu_f(bf2f(xv.w));
    *(ushort4*)(op + (size_t)(pb + t0 * pstep) * C4) = make_ushort4(0, 0, 0, 0);

    ushort4 nxt = *(const ushort4*)(ip + (size_t)(pb + (t0 + dt) * pstep) * CB);
    for (int k = 1; k < 64; k++) {
        const int tt = t0 + dt * k;
        ushort4 cur = nxt;
        if (k < 63)
            nxt = *(const ushort4*)(ip + (size_t)(pb + (tt + dt) * pstep) * CB);
        s0 = relu_f(fmaf(s0, w4.x, b4.x + bf2f(cur.x)));
        s1 = relu_f(fmaf(s1, w4.y, b4.y + bf2f(cur.y)));
        s2 = relu_f(fmaf(s2, w4.z, b4.z + bf2f(cur.z)));
        s3 = relu_f(fmaf(s3, w4.w, b4.w + bf2f(cur.w)));
        ushort4 o; o.x = f2bf(s0); o.y = f2bf(s1); o.z = f2bf(s2); o.w = f2bf(s3);
        *(ushort4*)(op + (size_t)(pb + tt * pstep) * C4) = o;
    }
}

// ---------------------------------------------------------------------------
// ws map (bytes):  [0,16M) xT | [16M,80M) concat_T | [80M,96M) out0/mid |
//                  [96M,+0.5M) wA | +2M wB | +2M wC   (total ~100.5MB)
// d_out written only by the final GEMM (full 32MB fp32 channel-first).
// The reference's conv3x3 "attention" branch is dead code -> skipped.
// ---------------------------------------------------------------------------
extern "C" void kernel_launch(void* const* d_in, const int* in_sizes, int n_in,
                              void* d_out, int out_size, void* d_ws, size_t ws_size,
                              hipStream_t stream) {
    const float* x     = (const float*)d_in[0];
    const float* cin_w = (const float*)d_in[7];
    const float* c2_w  = (const float*)d_in[8];
    const float* c3_w  = (const float*)d_in[9];
    const float* i1_wu = (const float*)d_in[10];
    const float* i1_bu = (const float*)d_in[11];
    const float* i1_wr = (const float*)d_in[12];
    const float* i1_br = (const float*)d_in[13];
    const float* i1_wd = (const float*)d_in[14];
    const float* i1_bd = (const float*)d_in[15];
    const float* i1_wl = (const float*)d_in[16];
    const float* i1_bl = (const float*)d_in[17];
    const float* i2_wu = (const float*)d_in[18];
    const float* i2_bu = (const float*)d_in[19];
    const float* i2_wr = (const float*)d_in[20];
    const float* i2_br = (const float*)d_in[21];
    const float* i2_wd = (const float*)d_in[22];
    const float* i2_bd = (const float*)d_in[23];
    const float* i2_wl = (const float*)d_in[24];
    const float* i2_bl = (const float*)d_in[25];

    char* ws = (char*)d_ws;
    unsigned short* xT     = (unsigned short*)(ws);
    unsigned short* concat = (unsigned short*)(ws + (size_t)16 * 1024 * 1024);
    unsigned short* mid    = (unsigned short*)(ws + (size_t)80 * 1024 * 1024);
    unsigned short* wA     = (unsigned short*)(ws + (size_t)96 * 1024 * 1024);
    unsigned short* wB     = (unsigned short*)(wA + 512 * 512);
    unsigned short* wC     = (unsigned short*)(wB + 512 * 2048);

    // 1) weight casts (fp32 -> bf16, k-major already)
    cast_f32_bf16<<<256,  256, 0, stream>>>(cin_w, wA);
    cast_f32_bf16<<<1024, 256, 0, stream>>>(c2_w,  wB);
    cast_f32_bf16<<<1024, 256, 0, stream>>>(c3_w,  wC);

    // 2) x -> xT (channel-last bf16)
    transpose_cast_x<<<dim3(HW/64, CB/64, NB), 256, 0, stream>>>(x, xT);

    dim3 ggrid(PTOT/128, 4);

    // 3) out0_T = xT @ cin_w^T
    gemm_cl<512, 0><<<ggrid, 256, 0, stream>>>(xT, wA, mid);

    // 4) IRNN #1 -> concat_T  [u | r | d | l]
    scan_cl<<<128, 256, 0, stream>>>(mid, concat, i1_wu, i1_bu, 1, 64, 1, 0);
    scan_cl<<<128, 256, 0, stream>>>(mid, concat, i1_wr, i1_br, 64, 1, 0, 512);
    scan_cl<<<128, 256, 0, stream>>>(mid, concat, i1_wd, i1_bd, 1, 64, 0, 1024);
    scan_cl<<<128, 256, 0, stream>>>(mid, concat, i1_wl, i1_bl, 64, 1, 1, 1536);

    // 5) mid_T = concat_T @ c2_w^T
    gemm_cl<2048, 0><<<ggrid, 256, 0, stream>>>(concat, wB, mid);

    // 6) IRNN #2 -> concat_T
    scan_cl<<<128, 256, 0, stream>>>(mid, concat, i2_wu, i2_bu, 1, 64, 1, 0);
    scan_cl<<<128, 256, 0, stream>>>(mid, concat, i2_wr, i2_br, 64, 1, 0, 512);
    scan_cl<<<128, 256, 0, stream>>>(mid, concat, i2_wd, i2_bd, 1, 64, 0, 1024);
    scan_cl<<<128, 256, 0, stream>>>(mid, concat, i2_wl, i2_bl, 64, 1, 1, 1536);

    // 7) d_out = relu(concat_T @ c3_w^T), fp32 channel-first
    gemm_cl<2048, 1><<<ggrid, 256, 0, stream>>>(concat, wC, d_out);
}

// Round 3
// 143.986 us; speedup vs baseline: 7.8955x; 1.5192x over previous
//
#include <hip/hip_runtime.h>
#include <stdint.h>

// Geometry (fixed): B=4, C=512, H=W=64
#define NB 4
#define CB 512
#define HH 64
#define WW 64
#define HW 4096
#define C4 2048
#define PTOT (NB*HW)   // 16384 pixels across batch

typedef float  f32x4  __attribute__((ext_vector_type(4)));
typedef short  bf16x8 __attribute__((ext_vector_type(8)));

__device__ __forceinline__ float relu_f(float v){ return v > 0.f ? v : 0.f; }

__device__ __forceinline__ float bf2f(unsigned short u){
    union { uint32_t i; float f; } v; v.i = ((uint32_t)u) << 16; return v.f;
}
__device__ __forceinline__ unsigned short f2bf(float f){
    union { float f; uint32_t i; } v; v.f = f;
    uint32_t r = v.i + 0x7FFFu + ((v.i >> 16) & 1u);   // RNE
    return (unsigned short)(r >> 16);
}

__device__ __forceinline__ void gload16(const void* g, void* l){
    __builtin_amdgcn_global_load_lds(
        (const __attribute__((address_space(1))) uint32_t*)g,
        (__attribute__((address_space(3))) uint32_t*)l, 16, 0, 0);
}

// ---------------------------------------------------------------------------
// fp32 -> bf16 cast of the three weight matrices in one launch.
// sizes (float4 units): cin 65536 | c2 262144 | c3 262144  -> 589824 total
// ---------------------------------------------------------------------------
__global__ __launch_bounds__(256) void cast3_f32_bf16(
    const float* __restrict__ a, unsigned short* __restrict__ oa,
    const float* __restrict__ b, unsigned short* __restrict__ ob,
    const float* __restrict__ c, unsigned short* __restrict__ oc)
{
    int i = blockIdx.x * 256 + threadIdx.x;
    const float* src; unsigned short* dst; int j;
    if (i < 65536)        { src = a; dst = oa; j = i; }
    else if (i < 327680)  { src = b; dst = ob; j = i - 65536; }
    else                  { src = c; dst = oc; j = i - 327680; }
    float4 v = ((const float4*)src)[j];
    ushort4 o;
    o.x = f2bf(v.x); o.y = f2bf(v.y); o.z = f2bf(v.z); o.w = f2bf(v.w);
    ((ushort4*)dst)[j] = o;
}

// ---------------------------------------------------------------------------
// x [b][c][p] fp32  ->  xT [b*HW + p][c] bf16   (64x64 LDS tile transpose)
// ---------------------------------------------------------------------------
__global__ __launch_bounds__(256) void transpose_cast_x(
    const float* __restrict__ x, unsigned short* __restrict__ xT)
{
    __shared__ unsigned short tile[64][72];
    const int b  = blockIdx.z;
    const int p0 = blockIdx.x * 64;
    const int c0 = blockIdx.y * 64;
    const int t  = threadIdx.x;

    const int pl = (t & 15) * 4;
    const int cl = t >> 4;
    const float* src = x + ((size_t)b * CB + c0) * HW + p0;
    #pragma unroll
    for (int r = 0; r < 4; r++) {
        int c = cl + r * 16;
        float4 v = *(const float4*)(src + (size_t)c * HW + pl);
        tile[pl + 0][c] = f2bf(v.x);
        tile[pl + 1][c] = f2bf(v.y);
        tile[pl + 2][c] = f2bf(v.z);
        tile[pl + 3][c] = f2bf(v.w);
    }
    __syncthreads();
    unsigned short* dst = xT + ((size_t)b * HW + p0) * CB + c0;
    const int cl2 = (t & 15) * 4;
    const int pl2 = t >> 4;
    #pragma unroll
    for (int r = 0; r < 4; r++) {
        int p = pl2 + r * 16;
        ushort4 o = *(ushort4*)&tile[p][cl2];
        *(ushort4*)(dst + (size_t)p * CB + cl2) = o;
    }
}

// ---------------------------------------------------------------------------
// Channel-last MFMA GEMM, double-buffered 2-phase (T3-min + T5):
//   D[p][o] = sum_k A[p][k] * Bw[o][k]  (bf16 in, f32 acc)
// Tile 128p x 128o, BK=64, 4 waves, 4x4 16x16x32 frags/wave.
// LDS: 2 x (A 16K | B 16K) = 64K; stage next tile while MFMA-ing current.
// OUTMODE 0: bf16 [PTOT][512] channel-last; 1: fp32 [b][512][HW] + ReLU.
// ---------------------------------------------------------------------------
template<int K, int OUTMODE>
__global__ __launch_bounds__(256) void gemm_cl(
    const unsigned short* __restrict__ A,
    const unsigned short* __restrict__ Bw,
    void* __restrict__ out)
{
    __shared__ __align__(16) char lds[65536];

    const int t    = threadIdx.x;
    const int lane = t & 63;
    const int wid  = t >> 6;
    const int p0   = blockIdx.x * 128;
    const int o0   = blockIdx.y * 128;

    const int l15 = lane & 15;
    const int l4  = lane >> 4;
    const int wp  = (wid & 1) * 64;
    const int wo  = (wid >> 1) * 64;
    const int rowA = wp + l15;
    const int rowB = wo + l15;
    const int swzA = (rowA & 7) << 4;
    const int swzB = (rowB & 7) << 4;

    f32x4 acc[4][4];
    #pragma unroll
    for (int m = 0; m < 4; m++)
        #pragma unroll
        for (int n = 0; n < 4; n++) acc[m][n] = (f32x4)0.f;

    const int srow  = t >> 3;
    const int scolb = (t & 7) * 16;

    auto STAGE = [&](int k0, char* base) {
        #pragma unroll
        for (int q = 0; q < 4; q++) {
            const int row = q * 32 + srow;
            const int kk  = k0 + ((scolb ^ ((row & 7) << 4)) >> 1);
            gload16(A  + (size_t)(p0 + row) * K + kk, base +         q * 4096 + wid * 1024);
            gload16(Bw + (size_t)(o0 + row) * K + kk, base + 16384 + q * 4096 + wid * 1024);
        }
    };
    auto COMPUTE = [&](const char* base) {
        const char* cA = base;
        const char* cB = base + 16384;
        #pragma unroll
        for (int kh = 0; kh < 2; kh++) {
            const int colb = kh * 64 + l4 * 16;
            bf16x8 a[4], b[4];
            #pragma unroll
            for (int m = 0; m < 4; m++)
                a[m] = *(const bf16x8*)(cA + (rowA + m * 16) * 128 + (colb ^ swzA));
            #pragma unroll
            for (int n = 0; n < 4; n++)
                b[n] = *(const bf16x8*)(cB + (rowB + n * 16) * 128 + (colb ^ swzB));
            __builtin_amdgcn_s_setprio(1);
            #pragma unroll
            for (int m = 0; m < 4; m++)
                #pragma unroll
                for (int n = 0; n < 4; n++)
                    acc[m][n] = __builtin_amdgcn_mfma_f32_16x16x32_bf16(
                                    a[m], b[n], acc[m][n], 0, 0, 0);
            __builtin_amdgcn_s_setprio(0);
        }
    };

    const int NT = K / 64;
    STAGE(0, lds);
    __syncthreads();                       // compiler drains vmcnt before barrier
    #pragma unroll 2
    for (int tt = 0; tt < NT - 1; ++tt) {
        char* cbase = lds + ((tt & 1) ? 32768 : 0);
        char* nbase = lds + ((tt & 1) ? 0 : 32768);
        STAGE((tt + 1) * 64, nbase);       // prefetch next K-tile
        COMPUTE(cbase);                    // MFMA current
        __syncthreads();                   // drain vmcnt+lgkm, swap
    }
    COMPUTE(lds + (((NT - 1) & 1) ? 32768 : 0));

    if (OUTMODE == 0) {
        unsigned short* op = (unsigned short*)out;
        #pragma unroll
        for (int m = 0; m < 4; m++)
            #pragma unroll
            for (int r = 0; r < 4; r++) {
                const int p = p0 + wp + m * 16 + l4 * 4 + r;
                #pragma unroll
                for (int n = 0; n < 4; n++) {
                    const int o = wo + n * 16 + l15 + o0;
                    op[(size_t)p * CB + o] = f2bf(acc[m][n][r]);
                }
            }
    } else {
        __syncthreads();                   // protect LDS reuse vs last COMPUTE reads
        float (*tl)[132] = (float(*)[132])lds;
        const int bb   = p0 >> 12;
        const int phw0 = p0 & (HW - 1);
        #pragma unroll
        for (int half = 0; half < 2; half++) {
            if ((wid >> 1) == half) {
                #pragma unroll
                for (int n = 0; n < 4; n++)
                    #pragma unroll
                    for (int m = 0; m < 4; m++)
                        #pragma unroll
                        for (int r = 0; r < 4; r++)
                            tl[n * 16 + l15][wp + m * 16 + l4 * 4 + r] = acc[m][n][r];
            }
            __syncthreads();
            const int orow = t >> 2;
            const int pseg = (t & 3) * 32;
            float* dst = (float*)out +
                ((size_t)(bb * CB + o0 + half * 64 + orow)) * HW + phw0 + pseg;
            #pragma unroll
            for (int j = 0; j < 8; j++) {
                float4 v = *(float4*)&tl[orow][pseg + j * 4];
                v.x = relu_f(v.x); v.y = relu_f(v.y); v.z = relu_f(v.z); v.w = relu_f(v.w);
                *(float4*)(dst + j * 4) = v;
            }
            __syncthreads();
        }
    }
}

// ---------------------------------------------------------------------------
// Fused 4-direction IRNN scan, channel-last, scalar channel per thread.
// grid (512, 4): blockIdx.y = dir (0=u,1=r,2=d,3=l). 131072 threads/dir
// -> 32 waves/CU total. Depth-8 rotating-register prefetch (static indices).
// in: [b*HW+p][512] bf16 ; out: [b*HW+p][2048] bf16 at dir*512.
// Scan: out[t0]=0; s=relu(x[t0]); s=relu(s*w+(b+x[t])); out[t]=s.
// ---------------------------------------------------------------------------
__global__ __launch_bounds__(256) void irnn_fused(
    const unsigned short* __restrict__ in, unsigned short* __restrict__ outc,
    const float* __restrict__ wu, const float* __restrict__ bu,
    const float* __restrict__ wr, const float* __restrict__ br,
    const float* __restrict__ wd, const float* __restrict__ bd,
    const float* __restrict__ wl, const float* __restrict__ bl)
{
    const int dir = blockIdx.y;
    const float* wv; const float* bv; int pstep, rev;
    if      (dir == 0) { wv = wu; bv = bu; pstep = 64; rev = 1; }  // up
    else if (dir == 1) { wv = wr; bv = br; pstep = 1;  rev = 0; }  // right
    else if (dir == 2) { wv = wd; bv = bd; pstep = 64; rev = 0; }  // down
    else               { wv = wl; bv = bl; pstep = 1;  rev = 1; }  // left
    const int dirOff = dir * 512;

    const int idx = blockIdx.x * 256 + threadIdx.x;  // 0..131071
    const int c = idx & 511;
    const int f = (idx >> 9) & 63;
    const int b = idx >> 15;
    const int fbase = (pstep == 64) ? f : f * 64;    // vert: fixed w=f ; horz: fixed h=f

    const float wc = wv[c], bc = bv[c];
    const int t0 = rev ? 63 : 0;
    const int dp = rev ? -pstep : pstep;
    const int istep = dp * CB;
    const int ostep = dp * C4;

    const unsigned short* ip = in   + ((size_t)b * HW + fbase + (size_t)t0 * pstep) * CB + c;
    unsigned short*       op = outc + ((size_t)b * HW + fbase + (size_t)t0 * pstep) * C4 + dirOff + c;

    float s = relu_f(bf2f(ip[0]));
    op[0] = 0;

    unsigned short v0 = ip[1*istep], v1 = ip[2*istep], v2 = ip[3*istep], v3 = ip[4*istep],
                   v4 = ip[5*istep], v5 = ip[6*istep], v6 = ip[7*istep], v7 = ip[8*istep];

#define DO(kk, vv) { s = relu_f(fmaf(s, wc, bc + bf2f(vv))); op[(kk)*ostep] = f2bf(s); }
    for (int g = 0; g < 6; ++g) {          // steps 1..48, prefetch 9..56
        const int k0 = 1 + 8 * g;
        DO(k0+0, v0); v0 = ip[(k0+ 8)*istep];
        DO(k0+1, v1); v1 = ip[(k0+ 9)*istep];
        DO(k0+2, v2); v2 = ip[(k0+10)*istep];
        DO(k0+3, v3); v3 = ip[(k0+11)*istep];
        DO(k0+4, v4); v4 = ip[(k0+12)*istep];
        DO(k0+5, v5); v5 = ip[(k0+13)*istep];
        DO(k0+6, v6); v6 = ip[(k0+14)*istep];
        DO(k0+7, v7); v7 = ip[(k0+15)*istep];
    }
    // steps 49..56 (in v0..v7), prefetch 57..63
    DO(49, v0); v0 = ip[57*istep];
    DO(50, v1); v1 = ip[58*istep];
    DO(51, v2); v2 = ip[59*istep];
    DO(52, v3); v3 = ip[60*istep];
    DO(53, v4); v4 = ip[61*istep];
    DO(54, v5); v5 = ip[62*istep];
    DO(55, v6); v6 = ip[63*istep];
    DO(56, v7);
    DO(57, v0); DO(58, v1); DO(59, v2); DO(60, v3);
    DO(61, v4); DO(62, v5); DO(63, v6);
#undef DO
}

// ---------------------------------------------------------------------------
// ws map: [0,16M) xT | [16M,80M) concat_T | [80M,96M) out0/mid |
//         [96M,..) bf16 weights (0.5M + 2M + 2M)
// Reference's conv3x3 "attention" branch is dead code -> skipped.
// ---------------------------------------------------------------------------
extern "C" void kernel_launch(void* const* d_in, const int* in_sizes, int n_in,
                              void* d_out, int out_size, void* d_ws, size_t ws_size,
                              hipStream_t stream) {
    const float* x     = (const float*)d_in[0];
    const float* cin_w = (const float*)d_in[7];
    const float* c2_w  = (const float*)d_in[8];
    const float* c3_w  = (const float*)d_in[9];
    const float* i1_wu = (const float*)d_in[10];
    const float* i1_bu = (const float*)d_in[11];
    const float* i1_wr = (const float*)d_in[12];
    const float* i1_br = (const float*)d_in[13];
    const float* i1_wd = (const float*)d_in[14];
    const float* i1_bd = (const float*)d_in[15];
    const float* i1_wl = (const float*)d_in[16];
    const float* i1_bl = (const float*)d_in[17];
    const float* i2_wu = (const float*)d_in[18];
    const float* i2_bu = (const float*)d_in[19];
    const float* i2_wr = (const float*)d_in[20];
    const float* i2_br = (const float*)d_in[21];
    const float* i2_wd = (const float*)d_in[22];
    const float* i2_bd = (const float*)d_in[23];
    const float* i2_wl = (const float*)d_in[24];
    const float* i2_bl = (const float*)d_in[25];

    char* ws = (char*)d_ws;
    unsigned short* xT     = (unsigned short*)(ws);
    unsigned short* concat = (unsigned short*)(ws + (size_t)16 * 1024 * 1024);
    unsigned short* mid    = (unsigned short*)(ws + (size_t)80 * 1024 * 1024);
    unsigned short* wA     = (unsigned short*)(ws + (size_t)96 * 1024 * 1024);
    unsigned short* wB     = (unsigned short*)(wA + 512 * 512);
    unsigned short* wC     = (unsigned short*)(wB + 512 * 2048);

    // 1) weight casts (one launch)
    cast3_f32_bf16<<<2304, 256, 0, stream>>>(cin_w, wA, c2_w, wB, c3_w, wC);

    // 2) x -> xT (channel-last bf16)
    transpose_cast_x<<<dim3(HW/64, CB/64, NB), 256, 0, stream>>>(x, xT);

    dim3 ggrid(PTOT/128, 4);
    dim3 sgrid(512, 4);

    // 3) out0_T = xT @ cin_w^T
    gemm_cl<512, 0><<<ggrid, 256, 0, stream>>>(xT, wA, mid);

    // 4) IRNN #1 -> concat_T  [u | r | d | l]
    irnn_fused<<<sgrid, 256, 0, stream>>>(mid, concat,
        i1_wu, i1_bu, i1_wr, i1_br, i1_wd, i1_bd, i1_wl, i1_bl);

    // 5) mid_T = concat_T @ c2_w^T
    gemm_cl<2048, 0><<<ggrid, 256, 0, stream>>>(concat, wB, mid);

    // 6) IRNN #2 -> concat_T
    irnn_fused<<<sgrid, 256, 0, stream>>>(mid, concat,
        i2_wu, i2_bu, i2_wr, i2_br, i2_wd, i2_bd, i2_wl, i2_bl);

    // 7) d_out = relu(concat_T @ c3_w^T), fp32 channel-first
    gemm_cl<2048, 1><<<ggrid, 256, 0, stream>>>(concat, wC, d_out);
}